// Round 9
// baseline (1737.519 us; speedup 1.0000x reference)
//
#include <hip/hip_runtime.h>
#include <stdint.h>
#include <math.h>

#define BB 8
#define NN 16384
#define CC 13
#define GG 512
#define KK 32

#define NEIGH_ELEMS (BB*GG*KK*CC)   // 1,703,936

// ---------------------------------------------------------------------------
// Pack: x[B,N,13] (fp32) -> f32 SoA planes px,py,pz (channels 4..6).
// ---------------------------------------------------------------------------
__global__ void pack_kernel(const float* __restrict__ x,
                            float* __restrict__ px, float* __restrict__ py,
                            float* __restrict__ pz) {
    int i = blockIdx.x * blockDim.x + threadIdx.x;
    if (i >= BB * NN) return;
    const float* p = x + (size_t)i * CC + 4;
    px[i] = p[0]; py[i] = p[1]; pz[i] = p[2];
}

// ---------------------------------------------------------------------------
// FPS v4: one block (1024 threads) per batch, 16 points/thread, coords
// PINNED via empty asm. R8 post-mortem: at 32 pts/thread the allocator
// SPILLED ~60 of 148 live values to scratch (VGPR_Count=88) and reloaded
// every step (~1.9K cyc/step). 16 pts/thread needs only ~84 VGPRs -> fits
// the allocator's observed comfort zone; pin blocks rematerialization.
// One barrier per step (parity partials, redundant 16-entry scan). Center
// fetched via scalar load (readfirstlane). fp32 math verbatim (bit-exact).
// ---------------------------------------------------------------------------
__global__ __launch_bounds__(1024, 4) void fps_kernel(const float* __restrict__ px,
                                                      const float* __restrict__ py,
                                                      const float* __restrict__ pz,
                                                      float* __restrict__ centers) {
    const int b = blockIdx.x;
    const int t = threadIdx.x;
    const float* PX = px + b * NN;
    const float* PY = py + b * NN;
    const float* PZ = pz + b * NN;

    float X[16], Y[16], Z[16], MD[16];
#pragma unroll
    for (int i = 0; i < 16; ++i) {
        int pos = t + (i << 10);
        X[i] = PX[pos]; Y[i] = PY[pos]; Z[i] = PZ[pos];
        MD[i] = 1e10f;   // init_d = 10000000000.0
        // Pin: values are asm-modified -> reload from global is illegal.
        asm volatile("" : "+v"(X[i]), "+v"(Y[i]), "+v"(Z[i]));
    }

    __shared__ float s_v[2][16];
    __shared__ int   s_p[2][16];

    int wp = 0;   // current center index (uniform across block)
    if (t == 0) {
        float* oc = centers + (size_t)b * GG * 3;
        oc[0] = PX[0]; oc[1] = PY[0]; oc[2] = PZ[0];
    }

    for (int g = 1; g < GG; ++g) {
        // scalar broadcast load of current center coords (uniform index)
        int swp = __builtin_amdgcn_readfirstlane(wp);
        float lx = PX[swp], ly = PY[swp], lz = PZ[swp];
        float bv = -1.0f;
        int bp = 0x7fffffff;
#pragma unroll
        for (int i = 0; i < 16; ++i) {
            float e0 = __fsub_rn(X[i], lx);
            float e1 = __fsub_rn(Y[i], ly);
            float e2 = __fsub_rn(Z[i], lz);
            float d  = __fadd_rn(__fadd_rn(__fmul_rn(e0, e0), __fmul_rn(e1, e1)),
                                 __fmul_rn(e2, e2));
            float m = fminf(MD[i], d);   // np.minimum
            MD[i] = m;
            // ascending-index scan + strict '>' keeps lowest index on ties
            if (m > bv) { bv = m; bp = t + (i << 10); }
        }
        // wave(64) butterfly argmax, tie -> lower flat index
#pragma unroll
        for (int off = 32; off >= 1; off >>= 1) {
            float ov = __shfl_xor(bv, off);
            int   op = __shfl_xor(bp, off);
            if (ov > bv || (ov == bv && op < bp)) { bv = ov; bp = op; }
        }
        int par = g & 1;
        int w = t >> 6;
        if ((t & 63) == 0) { s_v[par][w] = bv; s_p[par][w] = bp; }
        __syncthreads();
        // redundant scan of 16 partials by every thread (LDS broadcast reads)
        float wv = s_v[par][0]; int wi = s_p[par][0];
#pragma unroll
        for (int q = 1; q < 16; ++q) {
            float qv = s_v[par][q]; int qp = s_p[par][q];
            if (qv > wv || (qv == wv && qp < wi)) { wv = qv; wi = qp; }
        }
        wp = wi;
        if (t == 0) {
            float* oc = centers + ((size_t)b * GG + g) * 3;
            oc[0] = PX[wp]; oc[1] = PY[wp]; oc[2] = PZ[wp];
        }
        // no second barrier: parity buffer isolates next round's writes
    }
}

// ---------------------------------------------------------------------------
// KNN v2 + gather (unchanged from R8): one 256-thread block per center,
// 64 pts/thread, top-2 cache + rare global rescan; XCD swizzle keeps each
// batch's SoA L2-resident on one XCD. d2 math bit-exact vs golden.
// ---------------------------------------------------------------------------
__global__ __launch_bounds__(256, 8) void knn_kernel(const float* __restrict__ px,
                                                     const float* __restrict__ py,
                                                     const float* __restrict__ pz,
                                                     const float* __restrict__ x,
                                                     const float* __restrict__ centers,
                                                     float* __restrict__ out) {
    const int blk = blockIdx.x;
    const int bg  = ((blk & 7) << 9) | (blk >> 3);   // batch = blk&7 -> one XCD
    const int b   = bg >> 9;
    const int t   = threadIdx.x;

    const float* ctr = centers + (size_t)bg * 3;
    float cx = ctr[0], cy = ctr[1], cz = ctr[2];
    float cc2 = __fadd_rn(__fadd_rn(__fmul_rn(cx, cx), __fmul_rn(cy, cy)),
                          __fmul_rn(cz, cz));

    const float* PX = px + b * NN;
    const float* PY = py + b * NN;
    const float* PZ = pz + b * NN;

    float k1 = INFINITY, k2 = INFINITY;
    int   p1 = 0x7fffffff, p2 = 0x7fffffff;
    uint64_t mask = 0;   // consumed elements of my 64-pt chunk

#pragma unroll 4
    for (int i = 0; i < 64; ++i) {
        int pos = (i << 8) + t;           // coalesced
        float ax = PX[pos], ay = PY[pos], az = PZ[pos];
        float pp2 = __fadd_rn(__fadd_rn(__fmul_rn(ax, ax), __fmul_rn(ay, ay)),
                              __fmul_rn(az, az));
        float dot = fmaf(cz, az, fmaf(cy, ay, __fmul_rn(cx, ax)));
        float d2  = __fsub_rn(__fadd_rn(cc2, pp2), __fmul_rn(2.0f, dot));
        // ascending pos scan, strict '<': ties keep lower pos
        if (d2 < k1)      { k2 = k1; p2 = p1; k1 = d2; p1 = pos; }
        else if (d2 < k2) { k2 = d2; p2 = pos; }
    }

    __shared__ float s_v[2][4];
    __shared__ int   s_p[2][4];
    __shared__ int   s_chosen[KK];

    for (int j = 0; j < KK; ++j) {
        float v = k1; int vp = p1;
#pragma unroll
        for (int off = 32; off >= 1; off >>= 1) {
            float ov = __shfl_xor(v, off);
            int   op = __shfl_xor(vp, off);
            if (ov < v || (ov == v && op < vp)) { v = ov; vp = op; }
        }
        int par = j & 1;
        int w = t >> 6;
        if ((t & 63) == 0) { s_v[par][w] = v; s_p[par][w] = vp; }
        __syncthreads();
        // redundant scan of 4 partials by every thread
        float wv = s_v[par][0]; int wp = s_p[par][0];
#pragma unroll
        for (int q = 1; q < 4; ++q) {
            float qv = s_v[par][q]; int qp = s_p[par][q];
            if (qv < wv || (qv == wv && qp < wp)) { wv = qv; wp = qp; }
        }
        if (t == 0) s_chosen[j] = wp;
        if ((wp & 255) == t) {
            // I owned the extracted point: mark consumed, promote second
            mask |= 1ull << (wp >> 8);
            k1 = k2; p1 = p2;
            k2 = INFINITY; p2 = 0x7fffffff;
            if (p1 == 0x7fffffff && mask != 0xffffffffffffffffull) {
                // top-2 exhausted (rare): rebuild from unmasked points,
                // reloading coords from global; d2 bit-identical
                k1 = INFINITY;
#pragma unroll 1
                for (int i = 0; i < 64; ++i) {
                    if ((mask >> i) & 1ull) continue;
                    int pos = (i << 8) + t;
                    float ax = PX[pos], ay = PY[pos], az = PZ[pos];
                    float pp2 = __fadd_rn(__fadd_rn(__fmul_rn(ax, ax), __fmul_rn(ay, ay)),
                                          __fmul_rn(az, az));
                    float dot = fmaf(cz, az, fmaf(cy, ay, __fmul_rn(cx, ax)));
                    float d2  = __fsub_rn(__fadd_rn(cc2, pp2), __fmul_rn(2.0f, dot));
                    if (d2 < k1)      { k2 = k1; p2 = p1; k1 = d2; p1 = pos; }
                    else if (d2 < k2) { k2 = d2; p2 = pos; }
                }
            }
        }
        // no second barrier: parity buffer isolates next round's writes
    }
    __syncthreads();   // s_chosen visibility for gather

    // gather: 32 neighbors x 13 channels; subtract center from ch 4..6
    for (int v = t; v < KK * CC; v += 256) {
        int j = v / CC, c = v - j * CC;
        int pt = s_chosen[j] & (NN - 1);   // safety clamp (no-op when correct)
        float val = x[((size_t)b * NN + pt) * CC + c];
        if (c >= 4 && c < 7) {
            float cs = (c == 4) ? cx : ((c == 5) ? cy : cz);
            val = __fsub_rn(val, cs);
        }
        out[((size_t)bg * KK + j) * CC + c] = val;
    }
}

extern "C" void kernel_launch(void* const* d_in, const int* in_sizes, int n_in,
                              void* d_out, int out_size, void* d_ws, size_t ws_size,
                              hipStream_t stream) {
    const float* x = (const float*)d_in[0];
    float* out = (float*)d_out;
    float* centers = out + NEIGH_ELEMS;   // output 1 follows output 0, flat

    float* px = (float*)d_ws;
    float* py = px + BB * NN;
    float* pz = py + BB * NN;

    pack_kernel<<<(BB * NN + 255) / 256, 256, 0, stream>>>(x, px, py, pz);
    fps_kernel<<<BB, 1024, 0, stream>>>(px, py, pz, centers);
    knn_kernel<<<BB * GG, 256, 0, stream>>>(px, py, pz, x, centers, out);
}

// Round 10
// 1538.043 us; speedup vs baseline: 1.1297x; 1.1297x over previous
//
#include <hip/hip_runtime.h>
#include <stdint.h>
#include <math.h>

#define BB 8
#define NN 16384
#define CC 13
#define GG 512
#define KK 32

#define NEIGH_ELEMS (BB*GG*KK*CC)   // 1,703,936

// ---------------------------------------------------------------------------
// Pack: x[B,N,13] (fp32) -> f32 SoA planes px,py,pz (channels 4..6).
// ---------------------------------------------------------------------------
__global__ void pack_kernel(const float* __restrict__ x,
                            float* __restrict__ px, float* __restrict__ py,
                            float* __restrict__ pz) {
    int i = blockIdx.x * blockDim.x + threadIdx.x;
    if (i >= BB * NN) return;
    const float* p = x + (size_t)i * CC + 4;
    px[i] = p[0]; py[i] = p[1]; pz[i] = p[2];
}

// ---------------------------------------------------------------------------
// FPS v5: one block (512 threads) per batch, 32 pts/thread, coords pinned.
// KEY FIX (R8/R9 post-mortem): amdgpu_waves_per_eu(2,2) tells the allocator
// occupancy is capped at 2 waves/EU (1 block/CU), so reducing pressure below
// 256 VGPRs buys nothing -> it allocates the full ~150 regs instead of
// spilling to scratch (~3K cyc/step reload tax at VGPR=56..88).
// Winner coords are carried through butterfly+LDS partials (no dependent
// center load on the critical path). One parity barrier per step.
// fp32 math verbatim from R6 (bit-exact vs golden).
// ---------------------------------------------------------------------------
__global__ __launch_bounds__(512)
__attribute__((amdgpu_waves_per_eu(2, 2)))
void fps_kernel(const float* __restrict__ px,
                const float* __restrict__ py,
                const float* __restrict__ pz,
                float* __restrict__ centers) {
    const int b = blockIdx.x;
    const int t = threadIdx.x;
    const float* PX = px + b * NN;
    const float* PY = py + b * NN;
    const float* PZ = pz + b * NN;

    float X[32], Y[32], Z[32], MD[32];
#pragma unroll
    for (int i = 0; i < 32; ++i) {
        int pos = t + (i << 9);
        X[i] = PX[pos]; Y[i] = PY[pos]; Z[i] = PZ[pos];
        MD[i] = 1e10f;   // init_d = 10000000000.0
        // Pin: values are asm-modified -> reload from global is illegal.
        asm volatile("" : "+v"(X[i]), "+v"(Y[i]), "+v"(Z[i]));
    }

    __shared__ float s_v[2][8];
    __shared__ int   s_p[2][8];
    __shared__ float s_x[2][8], s_y[2][8], s_z[2][8];

    // current center coords (uniform across block after each reduction)
    float lx = PX[0], ly = PY[0], lz = PZ[0];
    if (t == 0) {
        float* oc = centers + (size_t)b * GG * 3;
        oc[0] = lx; oc[1] = ly; oc[2] = lz;
    }

    for (int g = 1; g < GG; ++g) {
        float bv = -1.0f;
        int bp = 0x7fffffff;
        float bx = 0.f, by = 0.f, bz = 0.f;
#pragma unroll
        for (int i = 0; i < 32; ++i) {
            float e0 = __fsub_rn(X[i], lx);
            float e1 = __fsub_rn(Y[i], ly);
            float e2 = __fsub_rn(Z[i], lz);
            float d  = __fadd_rn(__fadd_rn(__fmul_rn(e0, e0), __fmul_rn(e1, e1)),
                                 __fmul_rn(e2, e2));
            float m = fminf(MD[i], d);   // np.minimum
            MD[i] = m;
            // ascending-index scan + strict '>' keeps lowest index on ties
            if (m > bv) { bv = m; bp = t + (i << 9); bx = X[i]; by = Y[i]; bz = Z[i]; }
        }
        // wave(64) butterfly argmax with coord carry, tie -> lower index
#pragma unroll
        for (int off = 32; off >= 1; off >>= 1) {
            float ov = __shfl_xor(bv, off);
            int   op = __shfl_xor(bp, off);
            float ox = __shfl_xor(bx, off);
            float oy = __shfl_xor(by, off);
            float oz = __shfl_xor(bz, off);
            if (ov > bv || (ov == bv && op < bp)) { bv = ov; bp = op; bx = ox; by = oy; bz = oz; }
        }
        int par = g & 1;
        int w = t >> 6;
        if ((t & 63) == 0) {
            s_v[par][w] = bv; s_p[par][w] = bp;
            s_x[par][w] = bx; s_y[par][w] = by; s_z[par][w] = bz;
        }
        __syncthreads();
        // redundant scan of 8 partials by every thread (LDS broadcast reads),
        // carrying winner coords -> next center is in registers immediately
        float wv = s_v[par][0]; int wi = s_p[par][0];
        float wx = s_x[par][0], wy = s_y[par][0], wz = s_z[par][0];
#pragma unroll
        for (int q = 1; q < 8; ++q) {
            float qv = s_v[par][q]; int qp = s_p[par][q];
            if (qv > wv || (qv == wv && qp < wi)) {
                wv = qv; wi = qp;
                wx = s_x[par][q]; wy = s_y[par][q]; wz = s_z[par][q];
            }
        }
        lx = wx; ly = wy; lz = wz;
        if (t == 0) {
            float* oc = centers + ((size_t)b * GG + g) * 3;
            oc[0] = lx; oc[1] = ly; oc[2] = lz;
        }
        // no second barrier: parity buffer isolates next round's writes
    }
}

// ---------------------------------------------------------------------------
// KNN v2 + gather (unchanged from R8): one 256-thread block per center,
// 64 pts/thread, top-2 cache + rare global rescan; XCD swizzle keeps each
// batch's SoA L2-resident on one XCD. d2 math bit-exact vs golden.
// ---------------------------------------------------------------------------
__global__ __launch_bounds__(256, 8) void knn_kernel(const float* __restrict__ px,
                                                     const float* __restrict__ py,
                                                     const float* __restrict__ pz,
                                                     const float* __restrict__ x,
                                                     const float* __restrict__ centers,
                                                     float* __restrict__ out) {
    const int blk = blockIdx.x;
    const int bg  = ((blk & 7) << 9) | (blk >> 3);   // batch = blk&7 -> one XCD
    const int b   = bg >> 9;
    const int t   = threadIdx.x;

    const float* ctr = centers + (size_t)bg * 3;
    float cx = ctr[0], cy = ctr[1], cz = ctr[2];
    float cc2 = __fadd_rn(__fadd_rn(__fmul_rn(cx, cx), __fmul_rn(cy, cy)),
                          __fmul_rn(cz, cz));

    const float* PX = px + b * NN;
    const float* PY = py + b * NN;
    const float* PZ = pz + b * NN;

    float k1 = INFINITY, k2 = INFINITY;
    int   p1 = 0x7fffffff, p2 = 0x7fffffff;
    uint64_t mask = 0;   // consumed elements of my 64-pt chunk

#pragma unroll 4
    for (int i = 0; i < 64; ++i) {
        int pos = (i << 8) + t;           // coalesced
        float ax = PX[pos], ay = PY[pos], az = PZ[pos];
        float pp2 = __fadd_rn(__fadd_rn(__fmul_rn(ax, ax), __fmul_rn(ay, ay)),
                              __fmul_rn(az, az));
        float dot = fmaf(cz, az, fmaf(cy, ay, __fmul_rn(cx, ax)));
        float d2  = __fsub_rn(__fadd_rn(cc2, pp2), __fmul_rn(2.0f, dot));
        // ascending pos scan, strict '<': ties keep lower pos
        if (d2 < k1)      { k2 = k1; p2 = p1; k1 = d2; p1 = pos; }
        else if (d2 < k2) { k2 = d2; p2 = pos; }
    }

    __shared__ float s_v[2][4];
    __shared__ int   s_p[2][4];
    __shared__ int   s_chosen[KK];

    for (int j = 0; j < KK; ++j) {
        float v = k1; int vp = p1;
#pragma unroll
        for (int off = 32; off >= 1; off >>= 1) {
            float ov = __shfl_xor(v, off);
            int   op = __shfl_xor(vp, off);
            if (ov < v || (ov == v && op < vp)) { v = ov; vp = op; }
        }
        int par = j & 1;
        int w = t >> 6;
        if ((t & 63) == 0) { s_v[par][w] = v; s_p[par][w] = vp; }
        __syncthreads();
        // redundant scan of 4 partials by every thread
        float wv = s_v[par][0]; int wp = s_p[par][0];
#pragma unroll
        for (int q = 1; q < 4; ++q) {
            float qv = s_v[par][q]; int qp = s_p[par][q];
            if (qv < wv || (qv == wv && qp < wp)) { wv = qv; wp = qp; }
        }
        if (t == 0) s_chosen[j] = wp;
        if ((wp & 255) == t) {
            // I owned the extracted point: mark consumed, promote second
            mask |= 1ull << (wp >> 8);
            k1 = k2; p1 = p2;
            k2 = INFINITY; p2 = 0x7fffffff;
            if (p1 == 0x7fffffff && mask != 0xffffffffffffffffull) {
                // top-2 exhausted (rare): rebuild from unmasked points,
                // reloading coords from global; d2 bit-identical
                k1 = INFINITY;
#pragma unroll 1
                for (int i = 0; i < 64; ++i) {
                    if ((mask >> i) & 1ull) continue;
                    int pos = (i << 8) + t;
                    float ax = PX[pos], ay = PY[pos], az = PZ[pos];
                    float pp2 = __fadd_rn(__fadd_rn(__fmul_rn(ax, ax), __fmul_rn(ay, ay)),
                                          __fmul_rn(az, az));
                    float dot = fmaf(cz, az, fmaf(cy, ay, __fmul_rn(cx, ax)));
                    float d2  = __fsub_rn(__fadd_rn(cc2, pp2), __fmul_rn(2.0f, dot));
                    if (d2 < k1)      { k2 = k1; p2 = p1; k1 = d2; p1 = pos; }
                    else if (d2 < k2) { k2 = d2; p2 = pos; }
                }
            }
        }
        // no second barrier: parity buffer isolates next round's writes
    }
    __syncthreads();   // s_chosen visibility for gather

    // gather: 32 neighbors x 13 channels; subtract center from ch 4..6
    for (int v = t; v < KK * CC; v += 256) {
        int j = v / CC, c = v - j * CC;
        int pt = s_chosen[j] & (NN - 1);   // safety clamp (no-op when correct)
        float val = x[((size_t)b * NN + pt) * CC + c];
        if (c >= 4 && c < 7) {
            float cs = (c == 4) ? cx : ((c == 5) ? cy : cz);
            val = __fsub_rn(val, cs);
        }
        out[((size_t)bg * KK + j) * CC + c] = val;
    }
}

extern "C" void kernel_launch(void* const* d_in, const int* in_sizes, int n_in,
                              void* d_out, int out_size, void* d_ws, size_t ws_size,
                              hipStream_t stream) {
    const float* x = (const float*)d_in[0];
    float* out = (float*)d_out;
    float* centers = out + NEIGH_ELEMS;   // output 1 follows output 0, flat

    float* px = (float*)d_ws;
    float* py = px + BB * NN;
    float* pz = py + BB * NN;

    pack_kernel<<<(BB * NN + 255) / 256, 256, 0, stream>>>(x, px, py, pz);
    fps_kernel<<<BB, 512, 0, stream>>>(px, py, pz, centers);
    knn_kernel<<<BB * GG, 256, 0, stream>>>(px, py, pz, x, centers, out);
}